// Round 1
// 185.228 us; speedup vs baseline: 1.0495x; 1.0495x over previous
//
#include <hip/hip_runtime.h>

// Round 6: two structural changes.
// (1) Bond-vector exchange via DPP instead of LDS vbuf. Lane e needs all 8
//     v's of its group; traverse d in XOR order d = e^m:
//       m=1..3 : quad_perm xor on v
//       m=7    : row_half_mirror (lane^7 within each 8-lane half-row)
//       m=4..6 : quad_perm xor on the half-mirrored value
//     Weights are staged in xor-permuted slot order (W[d][f][e] -> column e,
//     slot f*8 + (e^d)) so lanes still read contiguous float4s.
//     Removes the per-site LDS round-trip (vbuf write->read, ~120+cy on the
//     critical path of all 390 sites) and 3-4 DS ops/site/wave.
// (2) Single fused kernel: 512-thread blocks, waves 0-3 = left chain,
//     waves 4-7 = right chain for the SAME 32 batches (both sides run 24
//     chunks + tail, so barriers align), then in-block combine at the label
//     site. Kills the second dispatch + drain and the VL/RV global round-trip.

#define NSITES 784
#define DIM    8
#define ODIM   10
#define LABEL  392
#define WST    160   // words per staged site: 8 columns * 20-word stride
#define XST    20    // xb row stride: 16 sites + 4 pad (float4-aligned, odd/32 banks ok)

// DPP ctrl encodings
#define QP_X1 0xB1   // quad_perm [1,0,3,2] : lane ^ 1
#define QP_X2 0x4E   // quad_perm [2,3,0,1] : lane ^ 2
#define QP_X3 0x1B   // quad_perm [3,2,1,0] : lane ^ 3
#define RHM   0x141  // row_half_mirror     : lane ^ 7 within each 8-lane group

template <int CTRL>
__device__ __forceinline__ float dppf(float v) {
    const int vi = __float_as_int(v);
    return __int_as_float(__builtin_amdgcn_update_dpp(vi, vi, CTRL, 0xF, 0xF, false));
}

// One MPS site: v_new[e] = (1-p)*sum_m v[e^m]*w0[m] + p*sum_m v[e^m]*w1[m]
// wsite points at this lane's 16-float column: [f=0: m=0..7][f=1: m=0..7]
__device__ __forceinline__ float site_step(float v, float p, const float* wsite) {
    const float4 w00 = *(const float4*)(wsite + 0);
    const float4 w01 = *(const float4*)(wsite + 4);
    const float4 w10 = *(const float4*)(wsite + 8);
    const float4 w11 = *(const float4*)(wsite + 12);
    const float t1 = dppf<QP_X1>(v);   // v[e^1]
    const float t2 = dppf<QP_X2>(v);   // v[e^2]
    const float t3 = dppf<QP_X3>(v);   // v[e^3]
    const float t7 = dppf<RHM>(v);     // v[e^7]
    const float t6 = dppf<QP_X1>(t7);  // v[e^6]
    const float t5 = dppf<QP_X2>(t7);  // v[e^5]
    const float t4 = dppf<QP_X3>(t7);  // v[e^4]
    float a0 = v * w00.x;
    float a1 = v * w10.x;
    a0 = fmaf(t1, w00.y, a0);  a1 = fmaf(t1, w10.y, a1);
    a0 = fmaf(t2, w00.z, a0);  a1 = fmaf(t2, w10.z, a1);
    a0 = fmaf(t3, w00.w, a0);  a1 = fmaf(t3, w10.w, a1);
    a0 = fmaf(t4, w01.x, a0);  a1 = fmaf(t4, w11.x, a1);
    a0 = fmaf(t5, w01.y, a0);  a1 = fmaf(t5, w11.y, a1);
    a0 = fmaf(t6, w01.z, a0);  a1 = fmaf(t6, w11.z, a1);
    a0 = fmaf(t7, w01.w, a0);  a1 = fmaf(t7, w11.w, a1);
    return fmaf(1.0f - p, a0, p * a1);
}

__global__ __launch_bounds__(512, 4) void mps_fused(
    const float* __restrict__ x,      // [B, N]
    const float* __restrict__ w0,     // [2, D]
    const float* __restrict__ Wl,     // [391, d, f, e]
    const float* __restrict__ wlab,   // [D, 2, D, O] = 1280 floats
    const float* __restrict__ Wr,     // [390, d, f, e]
    const float* __restrict__ wlast,  // [D, 2]
    float* __restrict__ out)          // [B, O]
{
    __shared__ float wb[2][2][16 * WST];  // [side][buf] 41.0 KB
    __shared__ float xb[2][2][32 * XST];  // [side][buf] 10.2 KB, [batch][site]
    __shared__ float wl[1280];            // label weights, 5.1 KB
    __shared__ float vout[2][256];        // [side][g*8+e],  2.0 KB

    const int tid  = threadIdx.x;
    const int side = tid >> 8;            // waves 0-3: left, waves 4-7: right
    const int stid = tid & 255;
    const int g    = stid >> 3;           // batch group 0..31
    const int e    = stid & 7;            // owned bond index
    const int b0   = blockIdx.x * 32;

    // stage label weights once (visibility covered by the chunk barriers)
    if (tid < 320)
        *(float4*)&wl[tid * 4] = *(const float4*)&wlab[tid * 4];

    // Stage chunk c (16 sites) of this side's weights + x into buffer bufi.
    // Weight scatter applies the xor permutation:
    //   left : W[d][f][e] -> wb[s][e*20 + f*8 + (e^d)]   (contract over d)
    //   right: W[d][f][e] -> wb[s][d*20 + f*8 + (e^d)]   (contract over e)
    auto stage = [&](int bufi, int c, int nt) {
        float* wdst = wb[side][bufi];
        float* xdst = xb[side][bufi];
        if (side == 0) {
            #pragma unroll
            for (int r = 0; r < 2; ++r) {
                const int cid = stid + 256 * r;      // 0..511
                const int s   = cid >> 5;            // site slot
                const int u   = cid & 31;
                const int d   = u >> 2;
                const int f   = (u >> 1) & 1;
                const int e0  = (u & 1) * 4;
                if (s < nt) {
                    const float4 w = *(const float4*)(Wl + (size_t)(c * 16 + s) * 128 + d * 16 + f * 8 + e0);
                    float* dst = wdst + s * WST + f * 8;
                    dst[(e0 + 0) * 20 + ((e0 + 0) ^ d)] = w.x;
                    dst[(e0 + 1) * 20 + ((e0 + 1) ^ d)] = w.y;
                    dst[(e0 + 2) * 20 + ((e0 + 2) ^ d)] = w.z;
                    dst[(e0 + 3) * 20 + ((e0 + 3) ^ d)] = w.w;
                }
            }
            #pragma unroll
            for (int r = 0; r < 2; ++r) {
                const int cid = stid + 256 * r;
                const int s   = cid >> 5;
                const int g2  = cid & 31;
                if (s < nt)
                    xdst[g2 * XST + s] = x[(size_t)(b0 + g2) * NSITES + 1 + c * 16 + s];
            }
        } else {
            #pragma unroll
            for (int r = 0; r < 2; ++r) {
                const int cid = stid + 256 * r;
                const int s   = cid >> 5;
                const int u   = cid & 31;
                const int d   = u >> 2;
                const int k   = u & 3;
                const int f   = k >> 1;
                const int e0  = (k & 1) * 4;
                if (s < nt) {
                    // float4 = W[d][f][e0..e0+3]
                    const float4 w = *(const float4*)(Wr + (size_t)(389 - c * 16 - s) * 128 + u * 4);
                    float* dst = wdst + s * WST + d * 20 + f * 8;
                    dst[(e0 + 0) ^ d] = w.x;
                    dst[(e0 + 1) ^ d] = w.y;
                    dst[(e0 + 2) ^ d] = w.z;
                    dst[(e0 + 3) ^ d] = w.w;
                }
            }
            #pragma unroll
            for (int r = 0; r < 2; ++r) {
                const int cid = stid + 256 * r;
                const int s   = cid >> 5;
                const int g2  = cid & 31;
                if (s < nt)
                    xdst[g2 * XST + s] = x[(size_t)(b0 + g2) * NSITES + 782 - c * 16 - s];
            }
        }
    };

    // boundary init
    float v;
    if (side == 0) {
        const float p = x[(size_t)(b0 + g) * NSITES + 0];
        v = fmaf(1.0f - p, w0[e], p * w0[DIM + e]);
    } else {
        const float p = x[(size_t)(b0 + g) * NSITES + (NSITES - 1)];
        v = fmaf(1.0f - p, wlast[e * 2], p * wlast[e * 2 + 1]);
    }

    stage(0, 0, 16);
    int buf = 0;

    const float* wp0 = &wb[side][0][e * 20];
    const float* wp1 = &wb[side][1][e * 20];
    const float* xp0 = &xb[side][0][g * XST];
    const float* xp1 = &xb[side][1][g * XST];

    #pragma unroll 1
    for (int c = 0; c < 24; ++c) {                 // 24 full chunks = 384 sites
        __syncthreads();                           // chunk c staged; buf^1 free
        if (c < 23) stage(buf ^ 1, c + 1, 16);
        else        stage(buf ^ 1, 24, side == 0 ? 7 : 6);   // tail chunk
        const float* wp = buf ? wp1 : wp0;
        const float* xp = buf ? xp1 : xp0;
        #pragma unroll
        for (int jb = 0; jb < 4; ++jb) {
            const float4 xq = *(const float4*)(xp + jb * 4);
            #pragma unroll
            for (int jj = 0; jj < 4; ++jj) {
                const int   j = jb * 4 + jj;
                const float p = (jj == 0) ? xq.x : (jj == 1) ? xq.y : (jj == 2) ? xq.z : xq.w;
                v = site_step(v, p, wp + j * WST);
            }
        }
        buf ^= 1;
    }

    __syncthreads();                               // tail staged
    {
        const int nt = side == 0 ? 7 : 6;
        const float* wp = buf ? wp1 : wp0;
        const float* xp = buf ? xp1 : xp0;
        for (int j = 0; j < nt; ++j)
            v = site_step(v, xp[j], wp + j * WST);
    }

    // publish bond vectors and combine in-block at the label site
    vout[side][stid] = v;
    __syncthreads();

    if (tid < 320) {                               // 32 batches x 10 outputs
        const int bl = tid / 10;
        const int o  = tid - bl * 10;
        const float p = x[(size_t)(b0 + bl) * NSITES + LABEL];
        const float q = 1.0f - p;
        const float* vl = &vout[0][bl * 8];
        const float* rv = &vout[1][bl * 8];
        float acc = 0.0f;
        #pragma unroll
        for (int d = 0; d < DIM; ++d) {
            const float vld = vl[d];
            #pragma unroll
            for (int ee = 0; ee < DIM; ++ee) {
                const float m = fmaf(q, wl[((d * 2 + 0) * DIM + ee) * ODIM + o],
                                     p * wl[((d * 2 + 1) * DIM + ee) * ODIM + o]);
                acc = fmaf(vld * rv[ee], m, acc);
            }
        }
        out[(size_t)(b0 + bl) * ODIM + o] = acc;
    }
}

extern "C" void kernel_launch(void* const* d_in, const int* in_sizes, int n_in,
                              void* d_out, int out_size, void* d_ws, size_t ws_size,
                              hipStream_t stream) {
    const float* x     = (const float*)d_in[0];
    const float* w0    = (const float*)d_in[1];
    const float* Wl    = (const float*)d_in[2];
    const float* wlab  = (const float*)d_in[3];
    const float* Wr    = (const float*)d_in[4];
    const float* wlast = (const float*)d_in[5];

    mps_fused<<<512, 512, 0, stream>>>(x, w0, Wl, wlab, Wr, wlast, (float*)d_out);
}